// Round 4
// baseline (2927.456 us; speedup 1.0000x reference)
//
#include <hip/hip_runtime.h>
#include <math.h>

// PCA_75307956568420: 128 x (64x64 symmetric eigenproblem) whose eigenvector
// SIGNS must match LAPACK ssyevd on the f32 gram. Full SSTEDC replication:
// Householder tridiag (dsytd2 'L') -> dstedc scale -> dlaed0 splits (16x4) ->
// DSTEQR base solves (QL/QR, dlartg/dlaev2 conventions) -> dlaed1/2/3 merges
// WITH faithful dlaed2 deflation (type-1 small-z, type-2 close-d Givens,
// f32 tolerance 8*2^-24*max) -> back-transform. f32-rounding at every level
// boundary keeps decision comparisons within ~1ulp of the reference pipeline.

#define NMAT 128
#define EPS32 5.9604644775390625e-8
#define SAFMIN32 1.1754943508222875e-38

static __device__ __forceinline__ double f32r(double x) { return (double)(float)x; }
static __device__ __forceinline__ double lapsign(double a, double b) {
  return (b >= 0.0) ? fabs(a) : -fabs(a);
}

__device__ __forceinline__ double wred_sum(double v) {
#pragma unroll
  for (int o = 32; o > 0; o >>= 1) v += __shfl_xor(v, o, 64);
  return v;
}
__device__ __forceinline__ double wred_max(double v) {
#pragma unroll
  for (int o = 32; o > 0; o >>= 1) v = fmax(v, __shfl_xor(v, o, 64));
  return v;
}

// ------- Kernel 1: column stats + normalized Gram (f64 acc, f32 out) -------
__global__ __launch_bounds__(256) void gram_kernel(const float* __restrict__ x,
                                                   float* __restrict__ gbuf) {
  const int bh = blockIdx.x, b = bh >> 4, h = bh & 15;
  const float* base = x + (size_t)b * 4096 * 1024 + h * 64;
  __shared__ double ls[4][64], lq[4][64];
  __shared__ int lc[4][64];
  __shared__ float sm[64], si[64];
  __shared__ float tile[64][68];
  const int tid = threadIdx.x, j = tid & 63, g = tid >> 6;

  double sum = 0.0, sumsq = 0.0;
  int cnt = 0;
  for (int s = g; s < 4096; s += 4) {
    float v = base[(size_t)s * 1024 + j];
    sum += v;
    sumsq += (double)v * (double)v;
    cnt += (v != 0.0f) ? 1 : 0;
  }
  ls[g][j] = sum; lq[g][j] = sumsq; lc[g][j] = cnt;
  __syncthreads();
  if (g == 0) {
    double S1 = 0.0, S2 = 0.0; int C = 0;
    for (int a = 0; a < 4; ++a) { S1 += ls[a][j]; S2 += lq[a][j]; C += lc[a][j]; }
    double m = (C > 0) ? S1 / (double)C : 0.0;
    double var = (C > 0) ? (S2 - 2.0 * m * S1 + 4096.0 * m * m) / (double)C : 0.0;
    var = fmax(var, 0.0);
    double sd = sqrt(var);
    sm[j] = (float)m;
    si[j] = (sd > 0.0) ? (float)(1.0 / sd) : 0.0f;
  }
  __syncthreads();

  const int ti = tid >> 4, tj = tid & 15;
  const float mj = sm[j], ivj = si[j];
  double acc[4][4];
#pragma unroll
  for (int r = 0; r < 4; ++r)
#pragma unroll
    for (int c = 0; c < 4; ++c) acc[r][c] = 0.0;

  for (int s0 = 0; s0 < 4096; s0 += 64) {
#pragma unroll 4
    for (int k = 0; k < 16; ++k) {
      int sl = g * 16 + k;
      float v = base[(size_t)(s0 + sl) * 1024 + j];
      unsigned long long nz = __ballot(v != 0.0f);
      tile[sl][j] = (nz != 0ULL) ? (v - mj) * ivj : 0.0f;
    }
    __syncthreads();
    for (int ss = 0; ss < 64; ++ss) {
      const float4 av = *(const float4*)&tile[ss][4 * ti];
      const float4 bv = *(const float4*)&tile[ss][4 * tj];
      float a_[4] = {av.x, av.y, av.z, av.w};
      float b_[4] = {bv.x, bv.y, bv.z, bv.w};
#pragma unroll
      for (int r = 0; r < 4; ++r)
#pragma unroll
        for (int c = 0; c < 4; ++c) acc[r][c] += (double)a_[r] * (double)b_[c];
    }
    __syncthreads();
  }
  float* G = gbuf + (size_t)bh * 4096;
#pragma unroll
  for (int r = 0; r < 4; ++r)
#pragma unroll
    for (int c = 0; c < 4; ++c)
      G[(4 * ti + r) * 64 + 4 * tj + c] = (float)acc[r][c];
}

// ----------------------------- DLARTG / DLAEV2 -----------------------------
static __device__ void dlartg_d(double f, double g, double& cs, double& sn,
                                double& r) {
  if (g == 0.0) { cs = 1.0; sn = 0.0; r = f; }
  else if (f == 0.0) { cs = 0.0; sn = 1.0; r = g; }
  else {
    r = sqrt(f * f + g * g);
    cs = f / r; sn = g / r;
    if (fabs(f) > fabs(g) && cs < 0.0) { cs = -cs; sn = -sn; r = -r; }
  }
}

static __device__ void dlaev2_d(double a, double b, double c, double& rt1,
                                double& rt2, double& cs1, double& sn1) {
  double sm = a + c, df = a - c, adf = fabs(df), tb = b + b, ab = fabs(tb);
  double acmx, acmn;
  if (fabs(a) > fabs(c)) { acmx = a; acmn = c; } else { acmx = c; acmn = a; }
  double rt;
  if (adf > ab) rt = adf * sqrt(1.0 + (ab / adf) * (ab / adf));
  else if (adf < ab) rt = ab * sqrt(1.0 + (adf / ab) * (adf / ab));
  else rt = ab * sqrt(2.0);
  int sgn1;
  if (sm < 0.0) {
    rt1 = 0.5 * (sm - rt); sgn1 = -1;
    rt2 = (acmx / rt1) * acmn - (b / rt1) * b;
  } else if (sm > 0.0) {
    rt1 = 0.5 * (sm + rt); sgn1 = 1;
    rt2 = (acmx / rt1) * acmn - (b / rt1) * b;
  } else { rt1 = 0.5 * rt; rt2 = -0.5 * rt; sgn1 = 1; }
  int sgn2; double cs;
  if (df >= 0.0) { cs = df + rt; sgn2 = 1; } else { cs = df - rt; sgn2 = -1; }
  double acs = fabs(cs);
  if (acs > ab) {
    double ct = -tb / cs;
    sn1 = 1.0 / sqrt(1.0 + ct * ct); cs1 = ct * sn1;
  } else {
    if (ab == 0.0) { cs1 = 1.0; sn1 = 0.0; }
    else {
      double tn = -cs / tb;
      cs1 = 1.0 / sqrt(1.0 + tn * tn); sn1 = tn * cs1;
    }
  }
  if (sgn1 == sgn2) { double tn = cs1; cs1 = -sn1; sn1 = tn; }
}

// ------------------------ DSTEQR (n=16, COMPZ='I') -------------------------
// Serial (one lane). Z block = Zs[base..base+15][base..base+15].
static __device__ void rot2cols(double (*Zs)[65], int base, int k1, int k2,
                                double c, double s) {
  for (int r = 0; r < 16; ++r) {
    double a = Zs[base + r][base + k1], b = Zs[base + r][base + k2];
    Zs[base + r][base + k1] = c * a + s * b;
    Zs[base + r][base + k2] = -s * a + c * b;
  }
}

static __device__ void dsteqr16(double* d, double* e, double (*Zs)[65],
                                int base, double* cw, double* sw) {
  const int n = 16, nm1 = 15;
  const double eps = EPS32, eps2 = EPS32 * EPS32;
  int l1 = 0, jtot = 0, nmaxit = n * 30;
  while (l1 < n) {
    if (l1 > 0) e[l1 - 1] = 0.0;
    int m;
    for (m = l1; m < nm1; ++m) {
      double tst = fabs(e[m]);
      if (tst == 0.0) break;
      if (tst <= (sqrt(fabs(d[m])) * sqrt(fabs(d[m + 1]))) * eps) {
        e[m] = 0.0; break;
      }
    }
    int l = l1, lend = m;
    l1 = m + 1;
    if (lend == l) continue;
    if (fabs(d[lend]) < fabs(d[l])) { int t = l; l = lend; lend = t; }
    if (lend > l) {  // ---- QL ----
      for (;;) {
        int mm;
        if (l != lend) {
          for (mm = l; mm < lend; ++mm) {
            double tst = e[mm] * e[mm];
            if (tst <= (eps2 * fabs(d[mm])) * fabs(d[mm + 1]) + SAFMIN32) break;
          }
        } else mm = lend;
        if (mm < lend) e[mm] = 0.0;
        double p = d[l];
        if (mm == l) { d[l] = p; ++l; if (l <= lend) continue; else break; }
        if (mm == l + 1) {
          double rt1, rt2, c, s;
          dlaev2_d(d[l], e[l], d[l + 1], rt1, rt2, c, s);
          rot2cols(Zs, base, l, l + 1, c, s);
          d[l] = rt1; d[l + 1] = rt2; e[l] = 0.0;
          l += 2; if (l <= lend) continue; else break;
        }
        if (jtot == nmaxit) break;
        ++jtot;
        double g = (d[l + 1] - p) / (2.0 * e[l]);
        double r = sqrt(g * g + 1.0);
        g = d[mm] - p + e[l] / (g + lapsign(r, g));
        double s = 1.0, c = 1.0; p = 0.0;
        for (int i = mm - 1; i >= l; --i) {
          double f = s * e[i], b = c * e[i];
          dlartg_d(g, f, c, s, r);
          if (i != mm - 1) e[i + 1] = r;
          g = d[i + 1] - p;
          r = (d[i] - g) * s + 2.0 * c * b;
          p = s * r;
          d[i + 1] = g + p;
          g = c * r - b;
          cw[i] = c; sw[i] = -s;
        }
        for (int k = mm - 1; k >= l; --k) rot2cols(Zs, base, k, k + 1, cw[k], sw[k]);
        d[l] -= p; e[l] = g;
      }
    } else {  // ---- QR ----
      for (;;) {
        int mm;
        if (l != lend) {
          for (mm = l; mm > lend; --mm) {
            double tst = e[mm - 1] * e[mm - 1];
            if (tst <= (eps2 * fabs(d[mm])) * fabs(d[mm - 1]) + SAFMIN32) break;
          }
        } else mm = lend;
        if (mm > lend) e[mm - 1] = 0.0;
        double p = d[l];
        if (mm == l) { d[l] = p; --l; if (l >= lend) continue; else break; }
        if (mm == l - 1) {
          double rt1, rt2, c, s;
          dlaev2_d(d[l - 1], e[l - 1], d[l], rt1, rt2, c, s);
          rot2cols(Zs, base, l - 1, l, c, s);
          d[l - 1] = rt1; d[l] = rt2; e[l - 1] = 0.0;
          l -= 2; if (l >= lend) continue; else break;
        }
        if (jtot == nmaxit) break;
        ++jtot;
        double g = (d[l - 1] - p) / (2.0 * e[l - 1]);
        double r = sqrt(g * g + 1.0);
        g = d[mm] - p + e[l - 1] / (g + lapsign(r, g));
        double s = 1.0, c = 1.0; p = 0.0;
        for (int i = mm; i <= l - 1; ++i) {
          double f = s * e[i], b = c * e[i];
          dlartg_d(g, f, c, s, r);
          if (i != mm) e[i - 1] = r;
          g = d[i] - p;
          r = (d[i + 1] - g) * s + 2.0 * c * b;
          p = s * r;
          d[i] = g + p;
          g = c * r - b;
          cw[i] = c; sw[i] = s;
        }
        for (int k = mm; k <= l - 1; ++k) rot2cols(Zs, base, k, k + 1, cw[k], sw[k]);
        d[l] -= p; e[l - 1] = g;
      }
    }
  }
  // final selection sort ascending, swap columns (dsteqr)
  for (int ii = 1; ii < n; ++ii) {
    int i = ii - 1, k = i; double p = d[i];
    for (int j = ii; j < n; ++j)
      if (d[j] < p) { k = j; p = d[j]; }
    if (k != i) {
      d[k] = d[i]; d[i] = p;
      for (int r = 0; r < 16; ++r) {
        double t = Zs[base + r][base + i];
        Zs[base + r][base + i] = Zs[base + r][base + k];
        Zs[base + r][base + k] = t;
      }
    }
  }
}

// ------------- D&C merge with faithful DLAED2 deflation (dlaed1/2/3) -------
static __device__ void merge_dc(int off, int n, double rho_in, int lane,
                                double (*Zs)[65], double (*Zn)[65], float* ScF,
                                double* dd, double* dlam, double* wz,
                                double* zt, double* lamv, double* zloc,
                                double* dloc, double* lamfin, double* dvalS,
                                int* indx, int* slist, int* dlist, int* dcolS) {
  const int N1 = n / 2;
  if (lane < n) {
    int r = (lane < N1) ? (off + N1 - 1) : (off + N1);
    double z = Zs[r][off + lane];
    if (rho_in < 0.0 && lane >= N1) z = -z;
    zloc[lane] = z * 0.70710678118654752440;
    dloc[lane] = dd[off + lane];
  }
  __syncthreads();
  const double rho = fabs(2.0 * rho_in);
  // stable DLAMRG merge order
  if (lane < n) {
    double a = dloc[lane];
    int pos;
    if (lane < N1) {
      int c2 = 0;
      for (int i = N1; i < n; ++i) c2 += (dloc[i] < a) ? 1 : 0;
      pos = lane + c2;
    } else {
      int c1 = 0;
      for (int i = 0; i < N1; ++i) c1 += (dloc[i] <= a) ? 1 : 0;
      pos = (lane - N1) + c1;
    }
    indx[pos] = lane;
  }
  __syncthreads();
  double mx = (lane < n) ? fmax(fabs(dloc[lane]), fabs(zloc[lane])) : 0.0;
  mx = wred_max(mx);
  const double tol = 8.0 * EPS32 * mx;
  __syncthreads();

  // ---- DLAED2 deflation scan (wave-uniform; rotations row-parallel) ----
  int K = 0, nD = 0;
  {
    int pj = -1, j = 0;
    for (; j < n; ++j) {
      int cj = indx[j];
      if (rho * fabs(zloc[cj]) <= tol) { dlist[nD] = cj; ++nD; }
      else { pj = cj; ++j; break; }
    }
    if (pj >= 0) {
      for (; j < n; ++j) {
        int nj = indx[j];
        if (rho * fabs(zloc[nj]) <= tol) { dlist[nD] = nj; ++nD; continue; }
        double s0 = zloc[pj], c0 = zloc[nj];
        double ta = sqrt(c0 * c0 + s0 * s0);  // DLAPY2 (values O(1))
        double tt = dloc[nj] - dloc[pj];
        double cc = c0 / ta, ss = -s0 / ta;
        if (fabs(tt * cc * ss) <= tol) {
          // type-2 deflation: DROT(Q(:,pj), Q(:,nj), cc, ss)
          zloc[nj] = ta; zloc[pj] = 0.0;
          {
            double a = Zs[lane][off + pj], b = Zs[lane][off + nj];
            Zs[lane][off + pj] = cc * a + ss * b;
            Zs[lane][off + nj] = cc * b - ss * a;
          }
          double ndp = dloc[pj] * cc * cc + dloc[nj] * ss * ss;
          dloc[nj] = dloc[pj] * ss * ss + dloc[nj] * cc * cc;
          dloc[pj] = ndp;
          dlist[nD] = pj; ++nD;
          pj = nj;
        } else {
          slist[K] = pj; ++K;
          pj = nj;
        }
      }
      slist[K] = pj; ++K;
    }
  }
  __syncthreads();
  // sort deflated by (updated) d ascending (stable)
  if (lane == 0) {
    for (int m = 0; m < nD; ++m) { dvalS[m] = dloc[dlist[m]]; dcolS[m] = dlist[m]; }
    for (int a = 1; a < nD; ++a) {
      double v = dvalS[a]; int ci = dcolS[a]; int b = a - 1;
      while (b >= 0 && dvalS[b] > v) { dvalS[b+1] = dvalS[b]; dcolS[b+1] = dcolS[b]; --b; }
      dvalS[b+1] = v; dcolS[b+1] = ci;
    }
  }
  __syncthreads();
  if (lane < K) { dlam[lane] = dloc[slist[lane]]; wz[lane] = zloc[slist[lane]]; }
  __syncthreads();

  // ---- secular roots (dlaed4-style, tau relative to nearest pole) ----
  if (lane < K) {
    int jl = lane, pjp; double lo, hi;
    double sumz2 = 0.0;
    for (int i = 0; i < K; ++i) sumz2 += wz[i] * wz[i];
    if (jl < K - 1) {
      double mid = 0.5 * (dlam[jl] + dlam[jl + 1]);
      double f = 1.0;
      for (int i = 0; i < K; ++i) f += rho * wz[i] * wz[i] / (dlam[i] - mid);
      double gaph = 0.5 * (dlam[jl + 1] - dlam[jl]);
      if (f > 0.0) { pjp = jl;     lo = 0.0;   hi = gaph; }
      else         { pjp = jl + 1; lo = -gaph; hi = 0.0;  }
    } else { pjp = K - 1; lo = 0.0; hi = rho * sumz2; }
    double sig = dlam[pjp];
    double tau = 0.5 * (lo + hi);
    for (int it = 0; it < 100; ++it) {
      double g = 1.0, gp = 0.0;
      for (int i = 0; i < K; ++i) {
        double den = (dlam[i] - sig) - tau;
        double q = wz[i] * wz[i] / den;
        g += rho * q;
        gp += rho * q / den;
      }
      if (g > 0.0) hi = tau; else lo = tau;
      double tn = tau - g / gp;
      if (!(tn > lo && tn < hi)) tn = 0.5 * (lo + hi);
      double df = fabs(tn - tau);
      tau = tn;
      if (df <= 2.3e-16 * (fabs(tau) + 1e-30)) break;
    }
    lamv[jl] = sig + tau;
    for (int i = 0; i < K; ++i)
      ScF[i * 65 + jl] = (float)((dlam[i] - sig) - tau);
  }
  __syncthreads();
  // ---- dlaed3 z-tilde: sign(ztilde)=sign(w) ----
  if (lane < K) {
    int i = lane;
    double wv = (double)ScF[i * 65 + i];
    for (int j2 = 0; j2 < K; ++j2) {
      if (j2 == i) continue;
      wv *= (double)ScF[i * 65 + j2] / (dlam[i] - dlam[j2]);
    }
    double mag = sqrt(fmax(-wv, 0.0));
    zt[i] = (wz[i] >= 0.0) ? mag : -mag;
  }
  __syncthreads();
  // ---- secular vectors (normalized positively) ----
  if (lane < K) {
    double nrm2 = 0.0;
    for (int i = 0; i < K; ++i) {
      double sv = zt[i] / (double)ScF[i * 65 + lane];
      ScF[i * 65 + lane] = (float)sv;
      nrm2 += sv * sv;
    }
    float inv = (float)(1.0 / sqrt(nrm2));
    for (int i = 0; i < K; ++i) ScF[i * 65 + lane] *= inv;
  }
  __syncthreads();
  // ---- build new columns into Zn at final (merged ascending) positions ----
  if (lane < K) {
    int cnt = 0;
    for (int m = 0; m < nD; ++m) cnt += (dvalS[m] < lamv[lane]) ? 1 : 0;
    int fp = lane + cnt;
    for (int c0 = 0; c0 < n; c0 += 16) {
      double res[16];
#pragma unroll
      for (int t = 0; t < 16; ++t) res[t] = 0.0;
      for (int i = 0; i < K; ++i) {
        double sv = (double)ScF[i * 65 + lane];
        int col = off + slist[i];
#pragma unroll
        for (int t = 0; t < 16; ++t) res[t] += Zs[off + c0 + t][col] * sv;
      }
#pragma unroll
      for (int t = 0; t < 16; ++t) Zn[c0 + t][fp] = res[t];
    }
    lamfin[fp] = lamv[lane];
  }
  __syncthreads();
  for (int m = 0; m < nD; ++m) {
    int cnt = 0;
    for (int jl = 0; jl < K; ++jl) cnt += (lamv[jl] <= dvalS[m]) ? 1 : 0;
    int fp = m + cnt;
    if (lane < n) Zn[lane][fp] = Zs[off + lane][off + dcolS[m]];
    if (lane == 0) lamfin[fp] = dvalS[m];
  }
  __syncthreads();
  if (lane < n) {
    for (int c = 0; c < n; ++c) Zs[off + lane][off + c] = Zn[lane][c];
    dd[off + lane] = f32r(lamfin[lane]);  // f32 level boundary
  }
  __syncthreads();
}

// ---------------- Kernel 2: eigensolver + oracle + output ------------------
__global__ __launch_bounds__(64, 1) void eig_kernel(float* __restrict__ gbuf) {
  const int bh = blockIdx.x, b = bh >> 4, h = bh & 15;
  const int lane = threadIdx.x;
  float* G = gbuf + (size_t)bh * 4096;

  __shared__ double Zs[64][65];
  __shared__ double Zn[64][65];
  __shared__ double varch[64][64];
  __shared__ double ScD[2080];
  __shared__ double dd[64], ee[64], tauv[64], varr[64], wv[64];
  __shared__ double dlam[64], wz[64], zt[64], lamv[64], zloc[64], dloc[64];
  __shared__ double lamfin[64], dvalS[64], dsave[64], esave[64];
  __shared__ double cwA[4][16], swA[4][16];
  __shared__ int indx[64], slist[64], dlist[64], dcolS[64];
  float* ScF = (float*)ScD;

  // ---- load gram into LDS (f64) ----
  double (*Zw)[65] = Zs;
  for (int r = 0; r < 64; ++r) Zw[r][lane] = (double)G[r * 64 + lane];
  __syncthreads();

  // ---- Householder tridiagonalization (dsytd2, UPLO='L') ----
  for (int i = 0; i < 63; ++i) {
    double xv = (lane >= i + 2) ? Zw[i][lane] : 0.0;
    double xn2 = wred_sum(xv * xv);
    double alpha = Zw[i][i + 1];
    double beta, taui;
    if (xn2 == 0.0) { taui = 0.0; beta = alpha; }
    else {
      double nrm = sqrt(alpha * alpha + xn2);
      beta = (alpha >= 0.0) ? -nrm : nrm;
      taui = (beta - alpha) / beta;
    }
    if (lane == 0) { dd[i] = Zw[i][i]; ee[i] = beta; tauv[i] = taui; }
    if (taui != 0.0) {
      double vl = (lane == i + 1) ? 1.0
                                  : ((lane >= i + 2) ? xv / (alpha - beta) : 0.0);
      varr[lane] = vl;
      if (lane >= i + 1) varch[i][lane] = vl;
      __syncthreads();
      double wr = 0.0;
      for (int c = i + 1; c < 64; ++c) wr += Zw[c][lane] * varr[c];
      wr *= taui;
      double wtv = wred_sum((lane >= i + 1) ? wr * vl : 0.0);
      wr -= 0.5 * taui * wtv * vl;
      wv[lane] = (lane >= i + 1) ? wr : 0.0;
      __syncthreads();
      if (lane >= i + 1) {
        double vc = vl, wc = wr;
        for (int r = i + 1; r < 64; ++r)
          Zw[r][lane] -= (varr[r] * wc + wv[r] * vc);
      }
      __syncthreads();
    } else {
      __syncthreads();
    }
  }
  if (lane == 0) dd[63] = Zw[63][63];
  __syncthreads();

  // ---- emulate f32 ssytrd output, sstedc scaling, dlaed0 corrections ----
  dd[lane] = f32r(dd[lane]);
  if (lane < 63) ee[lane] = f32r(ee[lane]);
  __syncthreads();
  double mx = fabs(dd[lane]);
  if (lane < 63) mx = fmax(mx, fabs(ee[lane]));
  const double orgnrm = wred_max(mx);
  dd[lane] = f32r(dd[lane] / orgnrm);
  if (lane < 63) ee[lane] = f32r(ee[lane] / orgnrm);
  __syncthreads();
  dsave[lane] = dd[lane];
  esave[lane] = (lane < 63) ? ee[lane] : 0.0;
  __syncthreads();
  if (lane == 0) {
    const int ms[3] = {15, 31, 47};
    for (int a = 0; a < 3; ++a) {
      double ae = fabs(ee[ms[a]]);
      dd[ms[a]] = f32r(dd[ms[a]] - ae);
      dd[ms[a] + 1] = f32r(dd[ms[a] + 1] - ae);
    }
  }
  __syncthreads();

  // ---- base solves: DSTEQR on 4 x 16 blocks (serial lanes 0,16,32,48) ----
  for (int r = 0; r < 64; ++r) Zs[r][lane] = (r == lane) ? 1.0 : 0.0;
  __syncthreads();
  if ((lane & 15) == 0) {
    int bb = lane >> 4;
    dsteqr16(dd + bb * 16, ee + bb * 16, Zs, bb * 16, cwA[bb], swA[bb]);
  }
  __syncthreads();
  dd[lane] = f32r(dd[lane]);  // f32 level boundary
  __syncthreads();

  // ---- merges: (16+16)A, (16+16)B, then 32+32 ----
  merge_dc(0, 32, ee[15], lane, Zs, Zn, ScF, dd, dlam, wz, zt, lamv, zloc,
           dloc, lamfin, dvalS, indx, slist, dlist, dcolS);
  merge_dc(32, 32, ee[47], lane, Zs, Zn, ScF, dd, dlam, wz, zt, lamv, zloc,
           dloc, lamfin, dvalS, indx, slist, dlist, dcolS);
  merge_dc(0, 64, ee[31], lane, Zs, Zn, ScF, dd, dlam, wz, zt, lamv, zloc,
           dloc, lamfin, dvalS, indx, slist, dlist, dcolS);

  // ---- ORACLE: ||T Z - Z L||oo on the scaled tridiagonal ----
  double tres = 0.0;
  {
    const double lam = dd[lane];
    for (int i = 0; i < 64; ++i) {
      double tv = dsave[i] * Zs[i][lane];
      if (i > 0) tv += esave[i - 1] * Zs[i - 1][lane];
      if (i < 63) tv += esave[i] * Zs[i + 1][lane];
      tres = fmax(tres, fabs(tv - lam * Zs[i][lane]));
    }
  }
  tres = wred_max(tres);
  const bool dc_bad = !(tres <= 2e-5);  // NaN-safe; f32-accurate pipeline

  // ---- back-transform: Z <- H(0) ... H(62) Z ----
  for (int i = 62; i >= 0; --i) {
    double ti = tauv[i];
    if (ti != 0.0) {
      varr[lane] = varch[i][lane];
      __syncthreads();
      double wc = 0.0;
      for (int r = i + 1; r < 64; ++r) wc += varr[r] * Zs[r][lane];
      wc *= ti;
      for (int r = i + 1; r < 64; ++r) Zs[r][lane] -= varr[r] * wc;
      __syncthreads();
    }
  }
  __syncthreads();

  const double sentinel = dc_bad ? 1.0e6 : 0.0;
  // ---- output: out[b, h*64+i, j] = w_j * V[j][i] / 8 ----
  const double wj = dd[lane] * orgnrm * 0.125;
  for (int i2 = 0; i2 < 64; ++i2) {
    G[i2 * 64 + lane] = (float)(wj * Zs[lane][i2] + sentinel);
  }
}

extern "C" void kernel_launch(void* const* d_in, const int* in_sizes, int n_in,
                              void* d_out, int out_size, void* d_ws,
                              size_t ws_size, hipStream_t stream) {
  (void)in_sizes; (void)n_in; (void)out_size; (void)d_ws; (void)ws_size;
  const float* x = (const float*)d_in[0];
  float* out = (float*)d_out;
  gram_kernel<<<dim3(NMAT), dim3(256), 0, stream>>>(x, out);
  eig_kernel<<<dim3(NMAT), dim3(64), 0, stream>>>(out);
}